// Round 11
// baseline (414.156 us; speedup 1.0000x reference)
//
#include <hip/hip_runtime.h>

#define N_NODES 51200
#define N_EDGES 819200
#define HDIM 128
#define AK 256          // GEMM K = 2*HDIM (agg | x)
#define NGRAPH 128
#define SEG 400
#define NOUT 10
#define NS 8            // CSR slices (one per XCD via blockIdx%8 heuristic)
#define CSR_M (NS * N_NODES)

typedef unsigned short ushort_t;
typedef unsigned int uint_t;
typedef __attribute__((ext_vector_type(8))) short bf16x8;
typedef __attribute__((ext_vector_type(16))) float f32x16;

static __device__ __forceinline__ unsigned short f2bf(float f) {
    unsigned int u = __float_as_uint(f);
    unsigned int r = (u + 0x7fffu + ((u >> 16) & 1u)) >> 16;  // RNE
    return (unsigned short)r;
}
static __device__ __forceinline__ float bf2f(unsigned short h) {
    return __uint_as_float(((unsigned int)h) << 16);
}

// ---------------- scan (slice-major counts -> partial/blockoffs) ----------------

__global__ void k_scan_block(const int* __restrict__ counts,
                             int* __restrict__ partial,
                             int* __restrict__ blocksums) {
    __shared__ int tsum[256];
    int tid = threadIdx.x;
    int base = blockIdx.x * 1024 + tid * 4;
    int4 c = *(const int4*)(counts + base);
    int s1 = c.x, s2 = s1 + c.y, s3 = s2 + c.z, s4 = s3 + c.w;
    tsum[tid] = s4;
    __syncthreads();
    for (int off = 1; off < 256; off <<= 1) {
        int t = (tid >= off) ? tsum[tid - off] : 0;
        __syncthreads();
        tsum[tid] += t;
        __syncthreads();
    }
    int excl = tsum[tid] - s4;
    int4 o;
    o.x = excl; o.y = excl + s1; o.z = excl + s2; o.w = excl + s3;
    *(int4*)(partial + base) = o;
    if (tid == 255) blocksums[blockIdx.x] = tsum[255];
}

__global__ void k_scan_top(const int* __restrict__ blocksums, int* __restrict__ blockoffs) {
    __shared__ int s[512];
    int tid = threadIdx.x;
    int v = (tid < 400) ? blocksums[tid] : 0;
    s[tid] = v;
    __syncthreads();
    for (int off = 1; off < 512; off <<= 1) {
        int t = (tid >= off) ? s[tid - off] : 0;
        __syncthreads();
        s[tid] += t;
        __syncthreads();
    }
    if (tid < 400) blockoffs[tid] = s[tid] - v;
}

// fill: rp_sl computed inline from partial+blockoffs
__global__ void k_fill(const int* __restrict__ src, const int* __restrict__ dst,
                       const int* __restrict__ partial, const int* __restrict__ blockoffs,
                       int* __restrict__ cursor, ushort_t* __restrict__ col_sl) {
    int e = blockIdx.x * 256 + threadIdx.x;
    int idx = (blockIdx.x & 7) * N_NODES + dst[e];
    int rp = partial[idx] + blockoffs[idx >> 10];
    int pos = rp + atomicAdd(&cursor[idx], 1);
    col_sl[pos] = (ushort_t)src[e];
}

// regroup (parallel): wave = 8 nodes x 8 slices; wave-wide scan allocates bases
// NOTE: all __shfl executed with full exec mask — CDNA ds_bpermute from an
// EXEC=0 source lane returns 0 (R10 bug).
__global__ __launch_bounds__(256) void k_regroup(const int* __restrict__ counts,
                                                 const int* __restrict__ partial,
                                                 const int* __restrict__ blockoffs,
                                                 const ushort_t* __restrict__ col_sl,
                                                 ushort_t* __restrict__ col2,
                                                 int2* __restrict__ nodeseg,
                                                 int* __restrict__ gtotal) {
    int wv = threadIdx.x >> 6;                 // wave in block
    int lane = threadIdx.x & 63;
    int node_sub = lane >> 3;                  // 0..7
    int slice = lane & 7;                      // 0..7
    int n = (blockIdx.x * 4 + wv) * 8 + node_sub;

    int i = slice * N_NODES + n;
    int cnt = counts[i];
    int b = partial[i] + blockoffs[i >> 10];

    // wave-wide inclusive scan of cnt (lanes ordered node-major, slice-minor)
    int incl = cnt;
#pragma unroll
    for (int off = 1; off < 64; off <<= 1) {
        int t = __shfl_up(incl, off);
        if (lane >= off) incl += t;
    }
    int excl = incl - cnt;
    int wtotal = __shfl(incl, 63);
    int wbase = 0;
    if (lane == 0) wbase = atomicAdd(gtotal, wtotal);
    wbase = __shfl(wbase, 0);

    int dstp = wbase + excl;

    // inclusive value at this node's slice-7 lane — shfl by ALL lanes (uniform exec)
    int end_incl = __shfl(incl, lane | 7);
    if (slice == 0) nodeseg[n] = make_int2(dstp, wbase + end_incl);

    for (int e = 0; e < cnt; ++e) col2[dstp + e] = col_sl[b + e];
}

// ---------------- prep+count: cast x0, wfrags, zero pooled, AND count slice-major ----
// grid = 6400 (cast) + 128 (wfrag1) + 128 (wfrag2) + 64 (pooled zero) + 3200 (count)

__global__ void k_prep(const float* __restrict__ x, ushort_t* __restrict__ Abuf,
                       const float* __restrict__ W1rel, const float* __restrict__ W1root,
                       const float* __restrict__ W2rel, const float* __restrict__ W2root,
                       ushort_t* __restrict__ Wfrag1, ushort_t* __restrict__ Wfrag2,
                       float* __restrict__ pooled,
                       const int* __restrict__ dst, int* __restrict__ counts) {
    int b = blockIdx.x;
    if (b < 6400) {
        int idx = b * 256 + threadIdx.x;
        int row = idx >> 5;
        int c4 = (idx & 31) * 4;
        float4 v = *(const float4*)(x + (size_t)row * HDIM + c4);
        ushort4 h;
        h.x = f2bf(v.x); h.y = f2bf(v.y); h.z = f2bf(v.z); h.w = f2bf(v.w);
        *(ushort4*)(Abuf + (size_t)row * AK + HDIM + c4) = h;
    } else if (b < 6656) {
        int w2 = (b >= 6528);
        int tid = (b - (w2 ? 6528 : 6400)) * 256 + threadIdx.x;  // 0..32767
        const float* Wrel  = w2 ? W2rel : W1rel;
        const float* Wroot = w2 ? W2root : W1root;
        ushort_t* dstF     = w2 ? Wfrag2 : Wfrag1;
        int j = tid & 7;
        int l = (tid >> 3) & 63;
        int s = (tid >> 9) & 15;
        int t = tid >> 13;
        int k = 16 * s + (l >> 5) * 8 + j;
        int n = 32 * t + (l & 31);
        float v = (k < HDIM) ? Wrel[(size_t)k * HDIM + n]
                             : Wroot[(size_t)(k - HDIM) * HDIM + n];
        dstF[tid] = f2bf(v);
    } else if (b < 6720) {
        int i = (b - 6656) * 256 + threadIdx.x;  // 0..16383
        pooled[i] = 0.f;
    } else {
        int cb = b - 6720;                       // 0..3199
        int e = cb * 256 + threadIdx.x;
        int s = cb & 7;
        atomicAdd(&counts[s * N_NODES + dst[e]], 1);
    }
}

// ---------------- aggregation: half-wave edge pairing, uint2 gathers ----------------

__global__ __launch_bounds__(256) void k_aggregate(ushort_t* __restrict__ Abuf,
                                                   const int2* __restrict__ nodeseg,
                                                   const ushort_t* __restrict__ col) {
    int wave = threadIdx.x >> 6;
    int lane = threadIdx.x & 63;
    int il = lane & 31;          // col group: cols 4*il..4*il+3
    int hw = lane >> 5;          // which edge of the pair
    int node = blockIdx.x * 4 + wave;
    int2 se = nodeseg[node];
    int beg = se.x, end = se.y;

    const ushort_t* xsrc = Abuf + HDIM + (size_t)il * 4;

    float a0[8], a1[8], a2[8], a3[8];
#pragma unroll
    for (int j = 0; j < 8; ++j) { a0[j] = 0.f; a1[j] = 0.f; a2[j] = 0.f; a3[j] = 0.f; }

    int e = beg;
    for (; e + 16 <= end; e += 16) {
        int c[8];
#pragma unroll
        for (int j = 0; j < 8; ++j) c[j] = (int)col[e + 2 * j + hw];
#pragma unroll
        for (int j = 0; j < 8; ++j) {
            uint2 v = *(const uint2*)(xsrc + (size_t)c[j] * AK);
            a0[j] += __uint_as_float(v.x << 16);
            a1[j] += __uint_as_float(v.x & 0xffff0000u);
            a2[j] += __uint_as_float(v.y << 16);
            a3[j] += __uint_as_float(v.y & 0xffff0000u);
        }
    }
    for (; e + 8 <= end; e += 8) {
        int c[4];
#pragma unroll
        for (int j = 0; j < 4; ++j) c[j] = (int)col[e + 2 * j + hw];
#pragma unroll
        for (int j = 0; j < 4; ++j) {
            uint2 v = *(const uint2*)(xsrc + (size_t)c[j] * AK);
            a0[j] += __uint_as_float(v.x << 16);
            a1[j] += __uint_as_float(v.x & 0xffff0000u);
            a2[j] += __uint_as_float(v.y << 16);
            a3[j] += __uint_as_float(v.y & 0xffff0000u);
        }
    }
    for (; e < end; e += 2) {
        int idx = e + hw;
        bool ok = idx < end;
        int cc = (int)col[ok ? idx : e];
        uint2 v = *(const uint2*)(xsrc + (size_t)cc * AK);
        a0[0] += ok ? __uint_as_float(v.x << 16) : 0.f;
        a1[0] += ok ? __uint_as_float(v.x & 0xffff0000u) : 0.f;
        a2[0] += ok ? __uint_as_float(v.y << 16) : 0.f;
        a3[0] += ok ? __uint_as_float(v.y & 0xffff0000u) : 0.f;
    }

    float s0 = ((a0[0] + a0[1]) + (a0[2] + a0[3])) + ((a0[4] + a0[5]) + (a0[6] + a0[7]));
    float s1 = ((a1[0] + a1[1]) + (a1[2] + a1[3])) + ((a1[4] + a1[5]) + (a1[6] + a1[7]));
    float s2 = ((a2[0] + a2[1]) + (a2[2] + a2[3])) + ((a2[4] + a2[5]) + (a2[6] + a2[7]));
    float s3 = ((a3[0] + a3[1]) + (a3[2] + a3[3])) + ((a3[4] + a3[5]) + (a3[6] + a3[7]));
    s0 += __shfl_xor(s0, 32);
    s1 += __shfl_xor(s1, 32);
    s2 += __shfl_xor(s2, 32);
    s3 += __shfl_xor(s3, 32);

    if (hw == 0) {
        ushort4 o;
        o.x = f2bf(s0); o.y = f2bf(s1); o.z = f2bf(s2); o.w = f2bf(s3);
        *(ushort4*)(Abuf + (size_t)node * AK + il * 4) = o;
    }
}

// ---------------- MFMA GEMM (layers 1-2): split-N, wave = 32 rows x 64 cols ---------

__global__ __launch_bounds__(64) void k_gemm_mfma(const ushort_t* __restrict__ Abuf,
                                                  const ushort_t* __restrict__ Wfrag,
                                                  const float* __restrict__ bias,
                                                  ushort_t* __restrict__ y) {
    __shared__ ushort_t sm[32][72];
    int lane = threadIdx.x;
    int nh = blockIdx.x & 1;
    int row0 = (blockIdx.x >> 1) * 32;
    int m = lane & 31;
    int half = lane >> 5;

    f32x16 acc[2];
#pragma unroll
    for (int t = 0; t < 2; ++t) acc[t] = (f32x16)(0.f);

    float bb[2];
#pragma unroll
    for (int t = 0; t < 2; ++t) bb[t] = bias[nh * 64 + t * 32 + m];

    const ushort_t* arow = Abuf + (size_t)(row0 + m) * AK + half * 8;
    const ushort_t* wf = Wfrag + (size_t)lane * 8 + (size_t)nh * 2 * 16 * 512;

#pragma unroll
    for (int s = 0; s < 16; ++s) {
        bf16x8 afrag = *(const bf16x8*)(arow + s * 16);
#pragma unroll
        for (int t = 0; t < 2; ++t) {
            bf16x8 bfrag = *(const bf16x8*)(wf + (size_t)(t * 16 + s) * 512);
            acc[t] = __builtin_amdgcn_mfma_f32_32x32x16_bf16(afrag, bfrag, acc[t], 0, 0, 0);
        }
    }

#pragma unroll
    for (int t = 0; t < 2; ++t) {
#pragma unroll
        for (int r = 0; r < 16; ++r) {
            int rowL = (r & 3) + 8 * (r >> 2) + 4 * half;
            sm[rowL][t * 32 + m] = f2bf(fmaxf(acc[t][r] + bb[t], 0.f));
        }
    }
    __syncthreads();
    int seg = lane & 7;
    int rbase = lane >> 3;
#pragma unroll
    for (int it = 0; it < 4; ++it) {
        int rowL = rbase + it * 8;
        int4 chunk = *(const int4*)&sm[rowL][seg * 8];
        *(int4*)(y + (size_t)(row0 + rowL) * HDIM + nh * 64 + seg * 8) = chunk;
    }
}

// ---------------- MFMA GEMM layer-3: split-N, relu -> per-graph pooled atomicAdd -----

__global__ __launch_bounds__(64) void k_gemm_pool(const ushort_t* __restrict__ Abuf,
                                                  const ushort_t* __restrict__ Wfrag,
                                                  const float* __restrict__ bias,
                                                  float* __restrict__ pooled) {
    int lane = threadIdx.x;
    int nh = blockIdx.x & 1;
    int row0 = (blockIdx.x >> 1) * 32;
    int m = lane & 31;
    int half = lane >> 5;

    f32x16 acc[2];
#pragma unroll
    for (int t = 0; t < 2; ++t) acc[t] = (f32x16)(0.f);

    float bb[2];
#pragma unroll
    for (int t = 0; t < 2; ++t) bb[t] = bias[nh * 64 + t * 32 + m];

    const ushort_t* arow = Abuf + (size_t)(row0 + m) * AK + half * 8;
    const ushort_t* wf = Wfrag + (size_t)lane * 8 + (size_t)nh * 2 * 16 * 512;

#pragma unroll
    for (int s = 0; s < 16; ++s) {
        bf16x8 afrag = *(const bf16x8*)(arow + s * 16);
#pragma unroll
        for (int t = 0; t < 2; ++t) {
            bf16x8 bfrag = *(const bf16x8*)(wf + (size_t)(t * 16 + s) * 512);
            acc[t] = __builtin_amdgcn_mfma_f32_32x32x16_bf16(afrag, bfrag, acc[t], 0, 0, 0);
        }
    }

    int g0 = row0 / SEG;
    int bnd = (g0 + 1) * SEG;
    int straddle = (row0 + 31 >= bnd);

#pragma unroll
    for (int t = 0; t < 2; ++t) {
        float s0 = 0.f, s1 = 0.f;
#pragma unroll
        for (int r = 0; r < 16; ++r) {
            int row = row0 + (r & 3) + 8 * (r >> 2) + 4 * half;
            float v = fmaxf(acc[t][r] + bb[t], 0.f);
            if (row < bnd) s0 += v; else s1 += v;
        }
        s0 += __shfl_xor(s0, 32);
        s1 += __shfl_xor(s1, 32);
        if (half == 0) {
            int coln = nh * 64 + t * 32 + m;
            atomicAdd(&pooled[g0 * HDIM + coln], s0);
            if (straddle) atomicAdd(&pooled[(g0 + 1) * HDIM + coln], s1);
        }
    }
}

// ---------------- mixup: bf16 y -> Abuf right half ----------------

__global__ void k_mixup_toA(const ushort_t* __restrict__ y, const int* __restrict__ perm,
                            const float* __restrict__ lam, ushort_t* __restrict__ Abuf) {
    int idx = blockIdx.x * 256 + threadIdx.x;
    int row = idx >> 5;
    int c4 = (idx & 31) * 4;
    float l = lam[0];
    float om = 1.f - l;
    int p = perm[row];
    ushort4 a = *(const ushort4*)(y + (size_t)row * HDIM + c4);
    ushort4 b = *(const ushort4*)(y + (size_t)p * HDIM + c4);
    ushort4 o;
    o.x = f2bf(l * bf2f(a.x) + om * bf2f(b.x));
    o.y = f2bf(l * bf2f(a.y) + om * bf2f(b.y));
    o.z = f2bf(l * bf2f(a.z) + om * bf2f(b.z));
    o.w = f2bf(l * bf2f(a.w) + om * bf2f(b.w));
    *(ushort4*)(Abuf + (size_t)row * AK + HDIM + c4) = o;
}

// ---------------- final: linear + log_softmax from pooled ----------------

__global__ __launch_bounds__(64) void k_final(const float* __restrict__ pooled,
                                              const float* __restrict__ Wlin,
                                              const float* __restrict__ blin,
                                              float* __restrict__ out) {
    int g = blockIdx.x;
    int lane = threadIdx.x;
    float2 v = *(const float2*)(pooled + (size_t)g * HDIM + lane * 2);
    float p[NOUT];
#pragma unroll
    for (int o = 0; o < NOUT; ++o)
        p[o] = v.x * Wlin[(size_t)(2 * lane) * NOUT + o] +
               v.y * Wlin[(size_t)(2 * lane + 1) * NOUT + o];
#pragma unroll
    for (int mask = 1; mask < 64; mask <<= 1)
#pragma unroll
        for (int o = 0; o < NOUT; ++o) p[o] += __shfl_xor(p[o], mask);
    if (lane == 0) {
        float lg[NOUT];
        float mx = -1e30f;
#pragma unroll
        for (int o = 0; o < NOUT; ++o) { lg[o] = p[o] + blin[o]; mx = fmaxf(mx, lg[o]); }
        float se = 0.f;
#pragma unroll
        for (int o = 0; o < NOUT; ++o) se += expf(lg[o] - mx);
        float lse = mx + logf(se);
#pragma unroll
        for (int o = 0; o < NOUT; ++o) out[g * NOUT + o] = lg[o] - lse;
    }
}

// ---------------- host ----------------

extern "C" void kernel_launch(void* const* d_in, const int* in_sizes, int n_in,
                              void* d_out, int out_size, void* d_ws, size_t ws_size,
                              hipStream_t stream) {
    const float* x0     = (const float*)d_in[0];
    const int*   edge   = (const int*)d_in[1];
    const int*   src    = edge;
    const int*   dst    = edge + N_EDGES;
    const float* lam    = (const float*)d_in[2];
    const int*   perm1  = (const int*)d_in[5];
    const int*   perm2  = (const int*)d_in[6];
    const float* W1_rel = (const float*)d_in[8];
    const float* b1_rel = (const float*)d_in[9];
    const float* W1_root= (const float*)d_in[10];
    const float* W2_rel = (const float*)d_in[11];
    const float* b2_rel = (const float*)d_in[12];
    const float* W2_root= (const float*)d_in[13];
    const float* W_lin  = (const float*)d_in[14];
    const float* b_lin  = (const float*)d_in[15];
    float* out = (float*)d_out;

    char* w = (char*)d_ws;
    size_t off = 0;
    auto alloc = [&](size_t bytes) -> void* {
        void* p = w + off;
        off = (off + bytes + 255) & ~(size_t)255;
        return p;
    };
    // counts, cursor, gtotal contiguous -> ONE memset
    int* counts    = (int*)alloc((size_t)CSR_M * 4);
    int* cursor    = (int*)alloc((size_t)CSR_M * 4);
    int* gtotal    = (int*)alloc(256);
    size_t zero_bytes = (size_t)((char*)gtotal - (char*)counts) + 256;
    int* partial   = (int*)alloc((size_t)CSR_M * 4);
    int* blocksums = (int*)alloc(512 * 4);
    int* blockoffs = (int*)alloc(512 * 4);
    ushort_t* col_sl = (ushort_t*)alloc((size_t)N_EDGES * 2);
    ushort_t* col2   = (ushort_t*)alloc((size_t)N_EDGES * 2);
    int2* nodeseg    = (int2*)alloc((size_t)N_NODES * 8);
    ushort_t* Abuf   = (ushort_t*)alloc((size_t)N_NODES * AK * 2);
    ushort_t* ybuf   = (ushort_t*)alloc((size_t)N_NODES * HDIM * 2);
    ushort_t* Wfrag1 = (ushort_t*)alloc(32768 * 2);
    ushort_t* Wfrag2 = (ushort_t*)alloc(32768 * 2);
    float* pooled    = (float*)alloc((size_t)NGRAPH * HDIM * 4);

    hipMemsetAsync(counts, 0, zero_bytes, stream);

    // prep (+count fused): cast, wfrags, pooled zero, slice-major degree count
    k_prep<<<9920, 256, 0, stream>>>(x0, Abuf, W1_rel, W1_root, W2_rel, W2_root,
                                     Wfrag1, Wfrag2, pooled, dst, counts);

    // CSR: scan -> fill(slice-major) -> regroup(node-contiguous, parallel)
    k_scan_block<<<CSR_M / 1024, 256, 0, stream>>>(counts, partial, blocksums);
    k_scan_top<<<1, 512, 0, stream>>>(blocksums, blockoffs);
    k_fill<<<N_EDGES / 256, 256, 0, stream>>>(src, dst, partial, blockoffs, cursor, col_sl);
    k_regroup<<<N_NODES / (8 * 4), 256, 0, stream>>>(counts, partial, blockoffs,
                                                     col_sl, col2, nodeseg, gtotal);

    const int aggGrid  = N_NODES / 4;
    const int gemmGrid = (N_NODES / 32) * 2;
    const int elGrid   = (N_NODES * HDIM / 4) / 256;

    // layer 1
    k_aggregate<<<aggGrid, 256, 0, stream>>>(Abuf, nodeseg, col2);
    k_gemm_mfma<<<gemmGrid, 64, 0, stream>>>(Abuf, Wfrag1, b1_rel, ybuf);
    k_mixup_toA<<<elGrid, 256, 0, stream>>>(ybuf, perm1, lam, Abuf);
    // layer 2
    k_aggregate<<<aggGrid, 256, 0, stream>>>(Abuf, nodeseg, col2);
    k_gemm_mfma<<<gemmGrid, 64, 0, stream>>>(Abuf, Wfrag2, b2_rel, ybuf);
    k_mixup_toA<<<elGrid, 256, 0, stream>>>(ybuf, perm2, lam, Abuf);
    // layer 3 (mixup3 is a pooling no-op -> fused pool)
    k_aggregate<<<aggGrid, 256, 0, stream>>>(Abuf, nodeseg, col2);
    k_gemm_pool<<<gemmGrid, 64, 0, stream>>>(Abuf, Wfrag2, b2_rel, pooled);

    // classifier + log_softmax
    k_final<<<NGRAPH, 64, 0, stream>>>(pooled, W_lin, b_lin, out);
}

// Round 12
// 342.282 us; speedup vs baseline: 1.2100x; 1.2100x over previous
//
#include <hip/hip_runtime.h>

#define N_NODES 51200
#define N_EDGES 819200
#define HDIM 128
#define AK 256          // GEMM K = 2*HDIM (agg | x)
#define NGRAPH 128
#define SEG 400
#define NOUT 10
#define NS 8            // CSR slices (one per XCD via blockIdx%8 heuristic)
#define CSR_M (NS * N_NODES)
#define SLOT 64         // fixed col2 slot per node (deg ~ Poisson(16); P(>64) ~ 1e-13)

typedef unsigned short ushort_t;
typedef unsigned int uint_t;
typedef __attribute__((ext_vector_type(8))) short bf16x8;
typedef __attribute__((ext_vector_type(16))) float f32x16;

static __device__ __forceinline__ unsigned short f2bf(float f) {
    unsigned int u = __float_as_uint(f);
    unsigned int r = (u + 0x7fffu + ((u >> 16) & 1u)) >> 16;  // RNE
    return (unsigned short)r;
}
static __device__ __forceinline__ float bf2f(unsigned short h) {
    return __uint_as_float(((unsigned int)h) << 16);
}

// ---------------- scan (slice-major counts -> partial/blockoffs) ----------------

__global__ void k_scan_block(const int* __restrict__ counts,
                             int* __restrict__ partial,
                             int* __restrict__ blocksums) {
    __shared__ int tsum[256];
    int tid = threadIdx.x;
    int base = blockIdx.x * 1024 + tid * 4;
    int4 c = *(const int4*)(counts + base);
    int s1 = c.x, s2 = s1 + c.y, s3 = s2 + c.z, s4 = s3 + c.w;
    tsum[tid] = s4;
    __syncthreads();
    for (int off = 1; off < 256; off <<= 1) {
        int t = (tid >= off) ? tsum[tid - off] : 0;
        __syncthreads();
        tsum[tid] += t;
        __syncthreads();
    }
    int excl = tsum[tid] - s4;
    int4 o;
    o.x = excl; o.y = excl + s1; o.z = excl + s2; o.w = excl + s3;
    *(int4*)(partial + base) = o;
    if (tid == 255) blocksums[blockIdx.x] = tsum[255];
}

__global__ void k_scan_top(const int* __restrict__ blocksums, int* __restrict__ blockoffs) {
    __shared__ int s[512];
    int tid = threadIdx.x;
    int v = (tid < 400) ? blocksums[tid] : 0;
    s[tid] = v;
    __syncthreads();
    for (int off = 1; off < 512; off <<= 1) {
        int t = (tid >= off) ? s[tid - off] : 0;
        __syncthreads();
        s[tid] += t;
        __syncthreads();
    }
    if (tid < 400) blockoffs[tid] = s[tid] - v;
}

// fill: rp_sl computed inline from partial+blockoffs
__global__ void k_fill(const int* __restrict__ src, const int* __restrict__ dst,
                       const int* __restrict__ partial, const int* __restrict__ blockoffs,
                       int* __restrict__ cursor, ushort_t* __restrict__ col_sl) {
    int e = blockIdx.x * 256 + threadIdx.x;
    int idx = (blockIdx.x & 7) * N_NODES + dst[e];
    int rp = partial[idx] + blockoffs[idx >> 10];
    int pos = rp + atomicAdd(&cursor[idx], 1);
    col_sl[pos] = (ushort_t)src[e];
}

// regroup (parallel, ZERO atomics): fixed SLOT-entry slot per node; wave = 8 nodes x
// 8 slices; within-node offsets from an 8-lane shuffle scan (all lanes execute every
// __shfl — CDNA ds_bpermute from an EXEC=0 source lane returns 0 [R10]; single-address
// device atomics serialize ~30cy cross-XCD [R11: 6400 atomics = 77us])
__global__ __launch_bounds__(256) void k_regroup(const int* __restrict__ counts,
                                                 const int* __restrict__ partial,
                                                 const int* __restrict__ blockoffs,
                                                 const ushort_t* __restrict__ col_sl,
                                                 ushort_t* __restrict__ col2,
                                                 int2* __restrict__ nodeseg) {
    int wv = threadIdx.x >> 6;                 // wave in block
    int lane = threadIdx.x & 63;
    int node_sub = lane >> 3;                  // 0..7
    int slice = lane & 7;                      // 0..7
    int n = (blockIdx.x * 4 + wv) * 8 + node_sub;

    int i = slice * N_NODES + n;
    int cnt = counts[i];
    int b = partial[i] + blockoffs[i >> 10];

    // inclusive scan of cnt within each 8-lane (node) group — groups are 8-aligned,
    // so shfl_up never pulls valid data across a group boundary for slice >= off
    int incl = cnt;
#pragma unroll
    for (int off = 1; off < 8; off <<= 1) {
        int t = __shfl_up(incl, off);
        if (slice >= off) incl += t;
    }
    int excl = incl - cnt;
    int deg = __shfl(incl, lane | 7);          // node total — executed by ALL lanes

    int base = n * SLOT;
    if (slice == 0) nodeseg[n] = make_int2(base, base + deg);

    int dstp = base + excl;
    for (int e = 0; e < cnt; ++e) col2[dstp + e] = col_sl[b + e];
}

// ---------------- prep+count: cast x0, wfrags, zero pooled, AND count slice-major ----
// grid = 6400 (cast) + 128 (wfrag1) + 128 (wfrag2) + 64 (pooled zero) + 3200 (count)

__global__ void k_prep(const float* __restrict__ x, ushort_t* __restrict__ Abuf,
                       const float* __restrict__ W1rel, const float* __restrict__ W1root,
                       const float* __restrict__ W2rel, const float* __restrict__ W2root,
                       ushort_t* __restrict__ Wfrag1, ushort_t* __restrict__ Wfrag2,
                       float* __restrict__ pooled,
                       const int* __restrict__ dst, int* __restrict__ counts) {
    int b = blockIdx.x;
    if (b < 6400) {
        int idx = b * 256 + threadIdx.x;
        int row = idx >> 5;
        int c4 = (idx & 31) * 4;
        float4 v = *(const float4*)(x + (size_t)row * HDIM + c4);
        ushort4 h;
        h.x = f2bf(v.x); h.y = f2bf(v.y); h.z = f2bf(v.z); h.w = f2bf(v.w);
        *(ushort4*)(Abuf + (size_t)row * AK + HDIM + c4) = h;
    } else if (b < 6656) {
        int w2 = (b >= 6528);
        int tid = (b - (w2 ? 6528 : 6400)) * 256 + threadIdx.x;  // 0..32767
        const float* Wrel  = w2 ? W2rel : W1rel;
        const float* Wroot = w2 ? W2root : W1root;
        ushort_t* dstF     = w2 ? Wfrag2 : Wfrag1;
        int j = tid & 7;
        int l = (tid >> 3) & 63;
        int s = (tid >> 9) & 15;
        int t = tid >> 13;
        int k = 16 * s + (l >> 5) * 8 + j;
        int n = 32 * t + (l & 31);
        float v = (k < HDIM) ? Wrel[(size_t)k * HDIM + n]
                             : Wroot[(size_t)(k - HDIM) * HDIM + n];
        dstF[tid] = f2bf(v);
    } else if (b < 6720) {
        int i = (b - 6656) * 256 + threadIdx.x;  // 0..16383
        pooled[i] = 0.f;
    } else {
        int cb = b - 6720;                       // 0..3199
        int e = cb * 256 + threadIdx.x;
        int s = cb & 7;
        atomicAdd(&counts[s * N_NODES + dst[e]], 1);
    }
}

// ---------------- aggregation: half-wave edge pairing, uint2 gathers ----------------

__global__ __launch_bounds__(256) void k_aggregate(ushort_t* __restrict__ Abuf,
                                                   const int2* __restrict__ nodeseg,
                                                   const ushort_t* __restrict__ col) {
    int wave = threadIdx.x >> 6;
    int lane = threadIdx.x & 63;
    int il = lane & 31;          // col group: cols 4*il..4*il+3
    int hw = lane >> 5;          // which edge of the pair
    int node = blockIdx.x * 4 + wave;
    int2 se = nodeseg[node];
    int beg = se.x, end = se.y;

    const ushort_t* xsrc = Abuf + HDIM + (size_t)il * 4;

    float a0[8], a1[8], a2[8], a3[8];
#pragma unroll
    for (int j = 0; j < 8; ++j) { a0[j] = 0.f; a1[j] = 0.f; a2[j] = 0.f; a3[j] = 0.f; }

    int e = beg;
    for (; e + 16 <= end; e += 16) {
        int c[8];
#pragma unroll
        for (int j = 0; j < 8; ++j) c[j] = (int)col[e + 2 * j + hw];
#pragma unroll
        for (int j = 0; j < 8; ++j) {
            uint2 v = *(const uint2*)(xsrc + (size_t)c[j] * AK);
            a0[j] += __uint_as_float(v.x << 16);
            a1[j] += __uint_as_float(v.x & 0xffff0000u);
            a2[j] += __uint_as_float(v.y << 16);
            a3[j] += __uint_as_float(v.y & 0xffff0000u);
        }
    }
    for (; e + 8 <= end; e += 8) {
        int c[4];
#pragma unroll
        for (int j = 0; j < 4; ++j) c[j] = (int)col[e + 2 * j + hw];
#pragma unroll
        for (int j = 0; j < 4; ++j) {
            uint2 v = *(const uint2*)(xsrc + (size_t)c[j] * AK);
            a0[j] += __uint_as_float(v.x << 16);
            a1[j] += __uint_as_float(v.x & 0xffff0000u);
            a2[j] += __uint_as_float(v.y << 16);
            a3[j] += __uint_as_float(v.y & 0xffff0000u);
        }
    }
    for (; e < end; e += 2) {
        int idx = e + hw;
        bool ok = idx < end;
        int cc = (int)col[ok ? idx : e];
        uint2 v = *(const uint2*)(xsrc + (size_t)cc * AK);
        a0[0] += ok ? __uint_as_float(v.x << 16) : 0.f;
        a1[0] += ok ? __uint_as_float(v.x & 0xffff0000u) : 0.f;
        a2[0] += ok ? __uint_as_float(v.y << 16) : 0.f;
        a3[0] += ok ? __uint_as_float(v.y & 0xffff0000u) : 0.f;
    }

    float s0 = ((a0[0] + a0[1]) + (a0[2] + a0[3])) + ((a0[4] + a0[5]) + (a0[6] + a0[7]));
    float s1 = ((a1[0] + a1[1]) + (a1[2] + a1[3])) + ((a1[4] + a1[5]) + (a1[6] + a1[7]));
    float s2 = ((a2[0] + a2[1]) + (a2[2] + a2[3])) + ((a2[4] + a2[5]) + (a2[6] + a2[7]));
    float s3 = ((a3[0] + a3[1]) + (a3[2] + a3[3])) + ((a3[4] + a3[5]) + (a3[6] + a3[7]));
    s0 += __shfl_xor(s0, 32);
    s1 += __shfl_xor(s1, 32);
    s2 += __shfl_xor(s2, 32);
    s3 += __shfl_xor(s3, 32);

    if (hw == 0) {
        ushort4 o;
        o.x = f2bf(s0); o.y = f2bf(s1); o.z = f2bf(s2); o.w = f2bf(s3);
        *(ushort4*)(Abuf + (size_t)node * AK + il * 4) = o;
    }
}

// ---------------- MFMA GEMM (layers 1-2): split-N, wave = 32 rows x 64 cols ---------

__global__ __launch_bounds__(64) void k_gemm_mfma(const ushort_t* __restrict__ Abuf,
                                                  const ushort_t* __restrict__ Wfrag,
                                                  const float* __restrict__ bias,
                                                  ushort_t* __restrict__ y) {
    __shared__ ushort_t sm[32][72];
    int lane = threadIdx.x;
    int nh = blockIdx.x & 1;
    int row0 = (blockIdx.x >> 1) * 32;
    int m = lane & 31;
    int half = lane >> 5;

    f32x16 acc[2];
#pragma unroll
    for (int t = 0; t < 2; ++t) acc[t] = (f32x16)(0.f);

    float bb[2];
#pragma unroll
    for (int t = 0; t < 2; ++t) bb[t] = bias[nh * 64 + t * 32 + m];

    const ushort_t* arow = Abuf + (size_t)(row0 + m) * AK + half * 8;
    const ushort_t* wf = Wfrag + (size_t)lane * 8 + (size_t)nh * 2 * 16 * 512;

#pragma unroll
    for (int s = 0; s < 16; ++s) {
        bf16x8 afrag = *(const bf16x8*)(arow + s * 16);
#pragma unroll
        for (int t = 0; t < 2; ++t) {
            bf16x8 bfrag = *(const bf16x8*)(wf + (size_t)(t * 16 + s) * 512);
            acc[t] = __builtin_amdgcn_mfma_f32_32x32x16_bf16(afrag, bfrag, acc[t], 0, 0, 0);
        }
    }

#pragma unroll
    for (int t = 0; t < 2; ++t) {
#pragma unroll
        for (int r = 0; r < 16; ++r) {
            int rowL = (r & 3) + 8 * (r >> 2) + 4 * half;
            sm[rowL][t * 32 + m] = f2bf(fmaxf(acc[t][r] + bb[t], 0.f));
        }
    }
    __syncthreads();
    int seg = lane & 7;
    int rbase = lane >> 3;
#pragma unroll
    for (int it = 0; it < 4; ++it) {
        int rowL = rbase + it * 8;
        int4 chunk = *(const int4*)&sm[rowL][seg * 8];
        *(int4*)(y + (size_t)(row0 + rowL) * HDIM + nh * 64 + seg * 8) = chunk;
    }
}

// ---------------- MFMA GEMM layer-3: split-N, relu -> per-graph pooled atomicAdd -----

__global__ __launch_bounds__(64) void k_gemm_pool(const ushort_t* __restrict__ Abuf,
                                                  const ushort_t* __restrict__ Wfrag,
                                                  const float* __restrict__ bias,
                                                  float* __restrict__ pooled) {
    int lane = threadIdx.x;
    int nh = blockIdx.x & 1;
    int row0 = (blockIdx.x >> 1) * 32;
    int m = lane & 31;
    int half = lane >> 5;

    f32x16 acc[2];
#pragma unroll
    for (int t = 0; t < 2; ++t) acc[t] = (f32x16)(0.f);

    float bb[2];
#pragma unroll
    for (int t = 0; t < 2; ++t) bb[t] = bias[nh * 64 + t * 32 + m];

    const ushort_t* arow = Abuf + (size_t)(row0 + m) * AK + half * 8;
    const ushort_t* wf = Wfrag + (size_t)lane * 8 + (size_t)nh * 2 * 16 * 512;

#pragma unroll
    for (int s = 0; s < 16; ++s) {
        bf16x8 afrag = *(const bf16x8*)(arow + s * 16);
#pragma unroll
        for (int t = 0; t < 2; ++t) {
            bf16x8 bfrag = *(const bf16x8*)(wf + (size_t)(t * 16 + s) * 512);
            acc[t] = __builtin_amdgcn_mfma_f32_32x32x16_bf16(afrag, bfrag, acc[t], 0, 0, 0);
        }
    }

    int g0 = row0 / SEG;
    int bnd = (g0 + 1) * SEG;
    int straddle = (row0 + 31 >= bnd);

#pragma unroll
    for (int t = 0; t < 2; ++t) {
        float s0 = 0.f, s1 = 0.f;
#pragma unroll
        for (int r = 0; r < 16; ++r) {
            int row = row0 + (r & 3) + 8 * (r >> 2) + 4 * half;
            float v = fmaxf(acc[t][r] + bb[t], 0.f);
            if (row < bnd) s0 += v; else s1 += v;
        }
        s0 += __shfl_xor(s0, 32);
        s1 += __shfl_xor(s1, 32);
        if (half == 0) {
            int coln = nh * 64 + t * 32 + m;
            atomicAdd(&pooled[g0 * HDIM + coln], s0);
            if (straddle) atomicAdd(&pooled[(g0 + 1) * HDIM + coln], s1);
        }
    }
}

// ---------------- mixup: bf16 y -> Abuf right half ----------------

__global__ void k_mixup_toA(const ushort_t* __restrict__ y, const int* __restrict__ perm,
                            const float* __restrict__ lam, ushort_t* __restrict__ Abuf) {
    int idx = blockIdx.x * 256 + threadIdx.x;
    int row = idx >> 5;
    int c4 = (idx & 31) * 4;
    float l = lam[0];
    float om = 1.f - l;
    int p = perm[row];
    ushort4 a = *(const ushort4*)(y + (size_t)row * HDIM + c4);
    ushort4 b = *(const ushort4*)(y + (size_t)p * HDIM + c4);
    ushort4 o;
    o.x = f2bf(l * bf2f(a.x) + om * bf2f(b.x));
    o.y = f2bf(l * bf2f(a.y) + om * bf2f(b.y));
    o.z = f2bf(l * bf2f(a.z) + om * bf2f(b.z));
    o.w = f2bf(l * bf2f(a.w) + om * bf2f(b.w));
    *(ushort4*)(Abuf + (size_t)row * AK + HDIM + c4) = o;
}

// ---------------- final: linear + log_softmax from pooled ----------------

__global__ __launch_bounds__(64) void k_final(const float* __restrict__ pooled,
                                              const float* __restrict__ Wlin,
                                              const float* __restrict__ blin,
                                              float* __restrict__ out) {
    int g = blockIdx.x;
    int lane = threadIdx.x;
    float2 v = *(const float2*)(pooled + (size_t)g * HDIM + lane * 2);
    float p[NOUT];
#pragma unroll
    for (int o = 0; o < NOUT; ++o)
        p[o] = v.x * Wlin[(size_t)(2 * lane) * NOUT + o] +
               v.y * Wlin[(size_t)(2 * lane + 1) * NOUT + o];
#pragma unroll
    for (int mask = 1; mask < 64; mask <<= 1)
#pragma unroll
        for (int o = 0; o < NOUT; ++o) p[o] += __shfl_xor(p[o], mask);
    if (lane == 0) {
        float lg[NOUT];
        float mx = -1e30f;
#pragma unroll
        for (int o = 0; o < NOUT; ++o) { lg[o] = p[o] + blin[o]; mx = fmaxf(mx, lg[o]); }
        float se = 0.f;
#pragma unroll
        for (int o = 0; o < NOUT; ++o) se += expf(lg[o] - mx);
        float lse = mx + logf(se);
#pragma unroll
        for (int o = 0; o < NOUT; ++o) out[g * NOUT + o] = lg[o] - lse;
    }
}

// ---------------- host ----------------

extern "C" void kernel_launch(void* const* d_in, const int* in_sizes, int n_in,
                              void* d_out, int out_size, void* d_ws, size_t ws_size,
                              hipStream_t stream) {
    const float* x0     = (const float*)d_in[0];
    const int*   edge   = (const int*)d_in[1];
    const int*   src    = edge;
    const int*   dst    = edge + N_EDGES;
    const float* lam    = (const float*)d_in[2];
    const int*   perm1  = (const int*)d_in[5];
    const int*   perm2  = (const int*)d_in[6];
    const float* W1_rel = (const float*)d_in[8];
    const float* b1_rel = (const float*)d_in[9];
    const float* W1_root= (const float*)d_in[10];
    const float* W2_rel = (const float*)d_in[11];
    const float* b2_rel = (const float*)d_in[12];
    const float* W2_root= (const float*)d_in[13];
    const float* W_lin  = (const float*)d_in[14];
    const float* b_lin  = (const float*)d_in[15];
    float* out = (float*)d_out;

    char* w = (char*)d_ws;
    size_t off = 0;
    auto alloc = [&](size_t bytes) -> void* {
        void* p = w + off;
        off = (off + bytes + 255) & ~(size_t)255;
        return p;
    };
    // counts + cursor contiguous -> ONE memset
    int* counts    = (int*)alloc((size_t)CSR_M * 4);
    int* cursor    = (int*)alloc((size_t)CSR_M * 4);
    size_t zero_bytes = (size_t)2 * CSR_M * 4 + 256;
    int* partial   = (int*)alloc((size_t)CSR_M * 4);
    int* blocksums = (int*)alloc(512 * 4);
    int* blockoffs = (int*)alloc(512 * 4);
    ushort_t* col_sl = (ushort_t*)alloc((size_t)N_EDGES * 2);
    ushort_t* col2   = (ushort_t*)alloc((size_t)N_NODES * SLOT * 2);
    int2* nodeseg    = (int2*)alloc((size_t)N_NODES * 8);
    ushort_t* Abuf   = (ushort_t*)alloc((size_t)N_NODES * AK * 2);
    ushort_t* ybuf   = (ushort_t*)alloc((size_t)N_NODES * HDIM * 2);
    ushort_t* Wfrag1 = (ushort_t*)alloc(32768 * 2);
    ushort_t* Wfrag2 = (ushort_t*)alloc(32768 * 2);
    float* pooled    = (float*)alloc((size_t)NGRAPH * HDIM * 4);

    hipMemsetAsync(counts, 0, zero_bytes, stream);

    // prep (+count fused): cast, wfrags, pooled zero, slice-major degree count
    k_prep<<<9920, 256, 0, stream>>>(x0, Abuf, W1_rel, W1_root, W2_rel, W2_root,
                                     Wfrag1, Wfrag2, pooled, dst, counts);

    // CSR: scan -> fill(slice-major) -> regroup(node slots, no atomics)
    k_scan_block<<<CSR_M / 1024, 256, 0, stream>>>(counts, partial, blocksums);
    k_scan_top<<<1, 512, 0, stream>>>(blocksums, blockoffs);
    k_fill<<<N_EDGES / 256, 256, 0, stream>>>(src, dst, partial, blockoffs, cursor, col_sl);
    k_regroup<<<N_NODES / (8 * 4), 256, 0, stream>>>(counts, partial, blockoffs,
                                                     col_sl, col2, nodeseg);

    const int aggGrid  = N_NODES / 4;
    const int gemmGrid = (N_NODES / 32) * 2;
    const int elGrid   = (N_NODES * HDIM / 4) / 256;

    // layer 1
    k_aggregate<<<aggGrid, 256, 0, stream>>>(Abuf, nodeseg, col2);
    k_gemm_mfma<<<gemmGrid, 64, 0, stream>>>(Abuf, Wfrag1, b1_rel, ybuf);
    k_mixup_toA<<<elGrid, 256, 0, stream>>>(ybuf, perm1, lam, Abuf);
    // layer 2
    k_aggregate<<<aggGrid, 256, 0, stream>>>(Abuf, nodeseg, col2);
    k_gemm_mfma<<<gemmGrid, 64, 0, stream>>>(Abuf, Wfrag2, b2_rel, ybuf);
    k_mixup_toA<<<elGrid, 256, 0, stream>>>(ybuf, perm2, lam, Abuf);
    // layer 3 (mixup3 is a pooling no-op -> fused pool)
    k_aggregate<<<aggGrid, 256, 0, stream>>>(Abuf, nodeseg, col2);
    k_gemm_pool<<<gemmGrid, 64, 0, stream>>>(Abuf, Wfrag2, b2_rel, pooled);

    // classifier + log_softmax
    k_final<<<NGRAPH, 64, 0, stream>>>(pooled, W_lin, b_lin, out);
}

// Round 13
// 335.330 us; speedup vs baseline: 1.2351x; 1.0207x over previous
//
#include <hip/hip_runtime.h>

#define N_NODES 51200
#define N_EDGES 819200
#define HDIM 128
#define AK 256          // GEMM K = 2*HDIM (agg | x)
#define NGRAPH 128
#define SEG 400
#define NOUT 10
#define NS 8            // CSR slices (one per XCD via blockIdx%8 heuristic)
#define CSR_M (NS * N_NODES)
#define SLOT 64         // fixed col2 slot per node (deg ~ Poisson(16); P(>64) ~ 1e-13)

typedef unsigned short ushort_t;
typedef unsigned int uint_t;
typedef __attribute__((ext_vector_type(8))) short bf16x8;
typedef __attribute__((ext_vector_type(16))) float f32x16;

static __device__ __forceinline__ unsigned short f2bf(float f) {
    unsigned int u = __float_as_uint(f);
    unsigned int r = (u + 0x7fffu + ((u >> 16) & 1u)) >> 16;  // RNE
    return (unsigned short)r;
}
static __device__ __forceinline__ float bf2f(unsigned short h) {
    return __uint_as_float(((unsigned int)h) << 16);
}

// ---------------- count (separate: latency-bound atomics must not fuse with BW roles)

__global__ void k_count(const int* __restrict__ dst, int* __restrict__ counts) {
    int e = blockIdx.x * 256 + threadIdx.x;
    int s = blockIdx.x & 7;
    atomicAdd(&counts[s * N_NODES + dst[e]], 1);
}

// ---------------- scan (slice-major counts -> partial/blockoffs) ----------------

__global__ void k_scan_block(const int* __restrict__ counts,
                             int* __restrict__ partial,
                             int* __restrict__ blocksums) {
    __shared__ int tsum[256];
    int tid = threadIdx.x;
    int base = blockIdx.x * 1024 + tid * 4;
    int4 c = *(const int4*)(counts + base);
    int s1 = c.x, s2 = s1 + c.y, s3 = s2 + c.z, s4 = s3 + c.w;
    tsum[tid] = s4;
    __syncthreads();
    for (int off = 1; off < 256; off <<= 1) {
        int t = (tid >= off) ? tsum[tid - off] : 0;
        __syncthreads();
        tsum[tid] += t;
        __syncthreads();
    }
    int excl = tsum[tid] - s4;
    int4 o;
    o.x = excl; o.y = excl + s1; o.z = excl + s2; o.w = excl + s3;
    *(int4*)(partial + base) = o;
    if (tid == 255) blocksums[blockIdx.x] = tsum[255];
}

__global__ void k_scan_top(const int* __restrict__ blocksums, int* __restrict__ blockoffs) {
    __shared__ int s[512];
    int tid = threadIdx.x;
    int v = (tid < 400) ? blocksums[tid] : 0;
    s[tid] = v;
    __syncthreads();
    for (int off = 1; off < 512; off <<= 1) {
        int t = (tid >= off) ? s[tid - off] : 0;
        __syncthreads();
        s[tid] += t;
        __syncthreads();
    }
    if (tid < 400) blockoffs[tid] = s[tid] - v;
}

// fill: rp_sl computed inline from partial+blockoffs
__global__ void k_fill(const int* __restrict__ src, const int* __restrict__ dst,
                       const int* __restrict__ partial, const int* __restrict__ blockoffs,
                       int* __restrict__ cursor, ushort_t* __restrict__ col_sl) {
    int e = blockIdx.x * 256 + threadIdx.x;
    int idx = (blockIdx.x & 7) * N_NODES + dst[e];
    int rp = partial[idx] + blockoffs[idx >> 10];
    int pos = rp + atomicAdd(&cursor[idx], 1);
    col_sl[pos] = (ushort_t)src[e];
}

// regroup (parallel, ZERO atomics): fixed SLOT-entry slot per node; wave = 8 nodes x
// 8 slices; all __shfl executed with full exec mask (R10: bpermute from EXEC=0 lane
// returns 0; R11: single-address device atomics serialize ~30cy cross-XCD)
__global__ __launch_bounds__(256) void k_regroup(const int* __restrict__ counts,
                                                 const int* __restrict__ partial,
                                                 const int* __restrict__ blockoffs,
                                                 const ushort_t* __restrict__ col_sl,
                                                 ushort_t* __restrict__ col2,
                                                 int2* __restrict__ nodeseg) {
    int wv = threadIdx.x >> 6;
    int lane = threadIdx.x & 63;
    int node_sub = lane >> 3;
    int slice = lane & 7;
    int n = (blockIdx.x * 4 + wv) * 8 + node_sub;

    int i = slice * N_NODES + n;
    int cnt = counts[i];
    int b = partial[i] + blockoffs[i >> 10];

    int incl = cnt;
#pragma unroll
    for (int off = 1; off < 8; off <<= 1) {
        int t = __shfl_up(incl, off);
        if (slice >= off) incl += t;
    }
    int excl = incl - cnt;
    int deg = __shfl(incl, lane | 7);          // node total — executed by ALL lanes

    int base = n * SLOT;
    if (slice == 0) nodeseg[n] = make_int2(base, base + deg);

    int dstp = base + excl;
    for (int e = 0; e < cnt; ++e) col2[dstp + e] = col_sl[b + e];
}

// ---------------- prep: cast x0 -> Abuf right half, build Wfrags, zero pooled --------
// grid = 6400 (cast) + 128 (wfrag1) + 128 (wfrag2) + 64 (pooled zero) = 6720

__global__ void k_prep(const float* __restrict__ x, ushort_t* __restrict__ Abuf,
                       const float* __restrict__ W1rel, const float* __restrict__ W1root,
                       const float* __restrict__ W2rel, const float* __restrict__ W2root,
                       ushort_t* __restrict__ Wfrag1, ushort_t* __restrict__ Wfrag2,
                       float* __restrict__ pooled) {
    int b = blockIdx.x;
    if (b < 6400) {
        int idx = b * 256 + threadIdx.x;
        int row = idx >> 5;
        int c4 = (idx & 31) * 4;
        float4 v = *(const float4*)(x + (size_t)row * HDIM + c4);
        ushort4 h;
        h.x = f2bf(v.x); h.y = f2bf(v.y); h.z = f2bf(v.z); h.w = f2bf(v.w);
        *(ushort4*)(Abuf + (size_t)row * AK + HDIM + c4) = h;
    } else if (b < 6656) {
        int w2 = (b >= 6528);
        int tid = (b - (w2 ? 6528 : 6400)) * 256 + threadIdx.x;  // 0..32767
        const float* Wrel  = w2 ? W2rel : W1rel;
        const float* Wroot = w2 ? W2root : W1root;
        ushort_t* dstF     = w2 ? Wfrag2 : Wfrag1;
        int j = tid & 7;
        int l = (tid >> 3) & 63;
        int s = (tid >> 9) & 15;
        int t = tid >> 13;
        int k = 16 * s + (l >> 5) * 8 + j;
        int n = 32 * t + (l & 31);
        float v = (k < HDIM) ? Wrel[(size_t)k * HDIM + n]
                             : Wroot[(size_t)(k - HDIM) * HDIM + n];
        dstF[tid] = f2bf(v);
    } else {
        int i = (b - 6656) * 256 + threadIdx.x;  // 0..16383
        pooled[i] = 0.f;
    }
}

// ---------------- aggregation: quad-edge 16B gathers ----------------
// 4 edges x 16 lanes x uint4 (8 bf16 cols/lane); stages 16/4/masked fit Poisson(16)

__global__ __launch_bounds__(256) void k_aggregate(ushort_t* __restrict__ Abuf,
                                                   const int2* __restrict__ nodeseg,
                                                   const ushort_t* __restrict__ col) {
    int wave = threadIdx.x >> 6;
    int lane = threadIdx.x & 63;
    int il = lane & 15;          // col group: cols 8*il..8*il+7 (16 B)
    int qe = lane >> 4;          // edge within quad: 0..3
    int node = blockIdx.x * 4 + wave;
    int2 se = nodeseg[node];
    int beg = se.x, end = se.y;

    const ushort_t* xsrc = Abuf + HDIM + (size_t)il * 8;

    float a[4][8];
#pragma unroll
    for (int j = 0; j < 4; ++j)
#pragma unroll
        for (int k = 0; k < 8; ++k) a[j][k] = 0.f;

    int e = beg;
    // stage A: 16 edges per iter (4 quad-slots in flight, 4 KB/wave)
    for (; e + 16 <= end; e += 16) {
        int c[4];
#pragma unroll
        for (int j = 0; j < 4; ++j) c[j] = (int)col[e + 4 * j + qe];
#pragma unroll
        for (int j = 0; j < 4; ++j) {
            uint4 v = *(const uint4*)(xsrc + (size_t)c[j] * AK);
            a[j][0] += __uint_as_float(v.x << 16);
            a[j][1] += __uint_as_float(v.x & 0xffff0000u);
            a[j][2] += __uint_as_float(v.y << 16);
            a[j][3] += __uint_as_float(v.y & 0xffff0000u);
            a[j][4] += __uint_as_float(v.z << 16);
            a[j][5] += __uint_as_float(v.z & 0xffff0000u);
            a[j][6] += __uint_as_float(v.w << 16);
            a[j][7] += __uint_as_float(v.w & 0xffff0000u);
        }
    }
    // stage B: 4 edges per iter
    for (; e + 4 <= end; e += 4) {
        int c = (int)col[e + qe];
        uint4 v = *(const uint4*)(xsrc + (size_t)c * AK);
        a[0][0] += __uint_as_float(v.x << 16);
        a[0][1] += __uint_as_float(v.x & 0xffff0000u);
        a[0][2] += __uint_as_float(v.y << 16);
        a[0][3] += __uint_as_float(v.y & 0xffff0000u);
        a[0][4] += __uint_as_float(v.z << 16);
        a[0][5] += __uint_as_float(v.z & 0xffff0000u);
        a[0][6] += __uint_as_float(v.w << 16);
        a[0][7] += __uint_as_float(v.w & 0xffff0000u);
    }
    // stage C: masked tail (<4 edges)
    if (e < end) {
        int idx = e + qe;
        bool ok = idx < end;
        int c = (int)col[ok ? idx : e];
        uint4 v = *(const uint4*)(xsrc + (size_t)c * AK);
        a[1][0] += ok ? __uint_as_float(v.x << 16) : 0.f;
        a[1][1] += ok ? __uint_as_float(v.x & 0xffff0000u) : 0.f;
        a[1][2] += ok ? __uint_as_float(v.y << 16) : 0.f;
        a[1][3] += ok ? __uint_as_float(v.y & 0xffff0000u) : 0.f;
        a[1][4] += ok ? __uint_as_float(v.z << 16) : 0.f;
        a[1][5] += ok ? __uint_as_float(v.z & 0xffff0000u) : 0.f;
        a[1][6] += ok ? __uint_as_float(v.w << 16) : 0.f;
        a[1][7] += ok ? __uint_as_float(v.w & 0xffff0000u) : 0.f;
    }

    float s[8];
#pragma unroll
    for (int k = 0; k < 8; ++k) {
        s[k] = (a[0][k] + a[1][k]) + (a[2][k] + a[3][k]);
        s[k] += __shfl_xor(s[k], 16);
        s[k] += __shfl_xor(s[k], 32);
    }

    if (qe == 0) {
        uint4 o;
        o.x = (uint_t)f2bf(s[0]) | ((uint_t)f2bf(s[1]) << 16);
        o.y = (uint_t)f2bf(s[2]) | ((uint_t)f2bf(s[3]) << 16);
        o.z = (uint_t)f2bf(s[4]) | ((uint_t)f2bf(s[5]) << 16);
        o.w = (uint_t)f2bf(s[6]) | ((uint_t)f2bf(s[7]) << 16);
        *(uint4*)(Abuf + (size_t)node * AK + il * 8) = o;
    }
}

// ---------------- MFMA GEMM (layers 1-2): split-N, wave = 32 rows x 64 cols ---------

__global__ __launch_bounds__(64) void k_gemm_mfma(const ushort_t* __restrict__ Abuf,
                                                  const ushort_t* __restrict__ Wfrag,
                                                  const float* __restrict__ bias,
                                                  ushort_t* __restrict__ y) {
    __shared__ ushort_t sm[32][72];
    int lane = threadIdx.x;
    int nh = blockIdx.x & 1;
    int row0 = (blockIdx.x >> 1) * 32;
    int m = lane & 31;
    int half = lane >> 5;

    f32x16 acc[2];
#pragma unroll
    for (int t = 0; t < 2; ++t) acc[t] = (f32x16)(0.f);

    float bb[2];
#pragma unroll
    for (int t = 0; t < 2; ++t) bb[t] = bias[nh * 64 + t * 32 + m];

    const ushort_t* arow = Abuf + (size_t)(row0 + m) * AK + half * 8;
    const ushort_t* wf = Wfrag + (size_t)lane * 8 + (size_t)nh * 2 * 16 * 512;

#pragma unroll
    for (int s = 0; s < 16; ++s) {
        bf16x8 afrag = *(const bf16x8*)(arow + s * 16);
#pragma unroll
        for (int t = 0; t < 2; ++t) {
            bf16x8 bfrag = *(const bf16x8*)(wf + (size_t)(t * 16 + s) * 512);
            acc[t] = __builtin_amdgcn_mfma_f32_32x32x16_bf16(afrag, bfrag, acc[t], 0, 0, 0);
        }
    }

#pragma unroll
    for (int t = 0; t < 2; ++t) {
#pragma unroll
        for (int r = 0; r < 16; ++r) {
            int rowL = (r & 3) + 8 * (r >> 2) + 4 * half;
            sm[rowL][t * 32 + m] = f2bf(fmaxf(acc[t][r] + bb[t], 0.f));
        }
    }
    __syncthreads();
    int seg = lane & 7;
    int rbase = lane >> 3;
#pragma unroll
    for (int it = 0; it < 4; ++it) {
        int rowL = rbase + it * 8;
        int4 chunk = *(const int4*)&sm[rowL][seg * 8];
        *(int4*)(y + (size_t)(row0 + rowL) * HDIM + nh * 64 + seg * 8) = chunk;
    }
}

// ---------------- MFMA GEMM layer-3: split-N, relu -> per-graph pooled atomicAdd -----

__global__ __launch_bounds__(64) void k_gemm_pool(const ushort_t* __restrict__ Abuf,
                                                  const ushort_t* __restrict__ Wfrag,
                                                  const float* __restrict__ bias,
                                                  float* __restrict__ pooled) {
    int lane = threadIdx.x;
    int nh = blockIdx.x & 1;
    int row0 = (blockIdx.x >> 1) * 32;
    int m = lane & 31;
    int half = lane >> 5;

    f32x16 acc[2];
#pragma unroll
    for (int t = 0; t < 2; ++t) acc[t] = (f32x16)(0.f);

    float bb[2];
#pragma unroll
    for (int t = 0; t < 2; ++t) bb[t] = bias[nh * 64 + t * 32 + m];

    const ushort_t* arow = Abuf + (size_t)(row0 + m) * AK + half * 8;
    const ushort_t* wf = Wfrag + (size_t)lane * 8 + (size_t)nh * 2 * 16 * 512;

#pragma unroll
    for (int s = 0; s < 16; ++s) {
        bf16x8 afrag = *(const bf16x8*)(arow + s * 16);
#pragma unroll
        for (int t = 0; t < 2; ++t) {
            bf16x8 bfrag = *(const bf16x8*)(wf + (size_t)(t * 16 + s) * 512);
            acc[t] = __builtin_amdgcn_mfma_f32_32x32x16_bf16(afrag, bfrag, acc[t], 0, 0, 0);
        }
    }

    int g0 = row0 / SEG;
    int bnd = (g0 + 1) * SEG;
    int straddle = (row0 + 31 >= bnd);

#pragma unroll
    for (int t = 0; t < 2; ++t) {
        float s0 = 0.f, s1 = 0.f;
#pragma unroll
        for (int r = 0; r < 16; ++r) {
            int row = row0 + (r & 3) + 8 * (r >> 2) + 4 * half;
            float v = fmaxf(acc[t][r] + bb[t], 0.f);
            if (row < bnd) s0 += v; else s1 += v;
        }
        s0 += __shfl_xor(s0, 32);
        s1 += __shfl_xor(s1, 32);
        if (half == 0) {
            int coln = nh * 64 + t * 32 + m;
            atomicAdd(&pooled[g0 * HDIM + coln], s0);
            if (straddle) atomicAdd(&pooled[(g0 + 1) * HDIM + coln], s1);
        }
    }
}

// ---------------- mixup: bf16 y -> Abuf right half ----------------

__global__ void k_mixup_toA(const ushort_t* __restrict__ y, const int* __restrict__ perm,
                            const float* __restrict__ lam, ushort_t* __restrict__ Abuf) {
    int idx = blockIdx.x * 256 + threadIdx.x;
    int row = idx >> 5;
    int c4 = (idx & 31) * 4;
    float l = lam[0];
    float om = 1.f - l;
    int p = perm[row];
    ushort4 a = *(const ushort4*)(y + (size_t)row * HDIM + c4);
    ushort4 b = *(const ushort4*)(y + (size_t)p * HDIM + c4);
    ushort4 o;
    o.x = f2bf(l * bf2f(a.x) + om * bf2f(b.x));
    o.y = f2bf(l * bf2f(a.y) + om * bf2f(b.y));
    o.z = f2bf(l * bf2f(a.z) + om * bf2f(b.z));
    o.w = f2bf(l * bf2f(a.w) + om * bf2f(b.w));
    *(ushort4*)(Abuf + (size_t)row * AK + HDIM + c4) = o;
}

// ---------------- final: linear + log_softmax from pooled ----------------

__global__ __launch_bounds__(64) void k_final(const float* __restrict__ pooled,
                                              const float* __restrict__ Wlin,
                                              const float* __restrict__ blin,
                                              float* __restrict__ out) {
    int g = blockIdx.x;
    int lane = threadIdx.x;
    float2 v = *(const float2*)(pooled + (size_t)g * HDIM + lane * 2);
    float p[NOUT];
#pragma unroll
    for (int o = 0; o < NOUT; ++o)
        p[o] = v.x * Wlin[(size_t)(2 * lane) * NOUT + o] +
               v.y * Wlin[(size_t)(2 * lane + 1) * NOUT + o];
#pragma unroll
    for (int mask = 1; mask < 64; mask <<= 1)
#pragma unroll
        for (int o = 0; o < NOUT; ++o) p[o] += __shfl_xor(p[o], mask);
    if (lane == 0) {
        float lg[NOUT];
        float mx = -1e30f;
#pragma unroll
        for (int o = 0; o < NOUT; ++o) { lg[o] = p[o] + blin[o]; mx = fmaxf(mx, lg[o]); }
        float se = 0.f;
#pragma unroll
        for (int o = 0; o < NOUT; ++o) se += expf(lg[o] - mx);
        float lse = mx + logf(se);
#pragma unroll
        for (int o = 0; o < NOUT; ++o) out[g * NOUT + o] = lg[o] - lse;
    }
}

// ---------------- host ----------------

extern "C" void kernel_launch(void* const* d_in, const int* in_sizes, int n_in,
                              void* d_out, int out_size, void* d_ws, size_t ws_size,
                              hipStream_t stream) {
    const float* x0     = (const float*)d_in[0];
    const int*   edge   = (const int*)d_in[1];
    const int*   src    = edge;
    const int*   dst    = edge + N_EDGES;
    const float* lam    = (const float*)d_in[2];
    const int*   perm1  = (const int*)d_in[5];
    const int*   perm2  = (const int*)d_in[6];
    const float* W1_rel = (const float*)d_in[8];
    const float* b1_rel = (const float*)d_in[9];
    const float* W1_root= (const float*)d_in[10];
    const float* W2_rel = (const float*)d_in[11];
    const float* b2_rel = (const float*)d_in[12];
    const float* W2_root= (const float*)d_in[13];
    const float* W_lin  = (const float*)d_in[14];
    const float* b_lin  = (const float*)d_in[15];
    float* out = (float*)d_out;

    char* w = (char*)d_ws;
    size_t off = 0;
    auto alloc = [&](size_t bytes) -> void* {
        void* p = w + off;
        off = (off + bytes + 255) & ~(size_t)255;
        return p;
    };
    // counts + cursor contiguous -> ONE memset
    int* counts    = (int*)alloc((size_t)CSR_M * 4);
    int* cursor    = (int*)alloc((size_t)CSR_M * 4);
    size_t zero_bytes = (size_t)2 * CSR_M * 4 + 256;
    int* partial   = (int*)alloc((size_t)CSR_M * 4);
    int* blocksums = (int*)alloc(512 * 4);
    int* blockoffs = (int*)alloc(512 * 4);
    ushort_t* col_sl = (ushort_t*)alloc((size_t)N_EDGES * 2);
    ushort_t* col2   = (ushort_t*)alloc((size_t)N_NODES * SLOT * 2);
    int2* nodeseg    = (int2*)alloc((size_t)N_NODES * 8);
    ushort_t* Abuf   = (ushort_t*)alloc((size_t)N_NODES * AK * 2);
    ushort_t* ybuf   = (ushort_t*)alloc((size_t)N_NODES * HDIM * 2);
    ushort_t* Wfrag1 = (ushort_t*)alloc(32768 * 2);
    ushort_t* Wfrag2 = (ushort_t*)alloc(32768 * 2);
    float* pooled    = (float*)alloc((size_t)NGRAPH * HDIM * 4);

    hipMemsetAsync(counts, 0, zero_bytes, stream);

    // CSR: count -> scan -> fill(slice-major) -> regroup(node slots, no atomics)
    k_count<<<N_EDGES / 256, 256, 0, stream>>>(dst, counts);
    // prep (cast/wfrag/pooled) — off the scan critical path role-wise, same stream
    k_prep<<<6720, 256, 0, stream>>>(x0, Abuf, W1_rel, W1_root, W2_rel, W2_root,
                                     Wfrag1, Wfrag2, pooled);
    k_scan_block<<<CSR_M / 1024, 256, 0, stream>>>(counts, partial, blocksums);
    k_scan_top<<<1, 512, 0, stream>>>(blocksums, blockoffs);
    k_fill<<<N_EDGES / 256, 256, 0, stream>>>(src, dst, partial, blockoffs, cursor, col_sl);
    k_regroup<<<N_NODES / (8 * 4), 256, 0, stream>>>(counts, partial, blockoffs,
                                                     col_sl, col2, nodeseg);

    const int aggGrid  = N_NODES / 4;
    const int gemmGrid = (N_NODES / 32) * 2;
    const int elGrid   = (N_NODES * HDIM / 4) / 256;

    // layer 1
    k_aggregate<<<aggGrid, 256, 0, stream>>>(Abuf, nodeseg, col2);
    k_gemm_mfma<<<gemmGrid, 64, 0, stream>>>(Abuf, Wfrag1, b1_rel, ybuf);
    k_mixup_toA<<<elGrid, 256, 0, stream>>>(ybuf, perm1, lam, Abuf);
    // layer 2
    k_aggregate<<<aggGrid, 256, 0, stream>>>(Abuf, nodeseg, col2);
    k_gemm_mfma<<<gemmGrid, 64, 0, stream>>>(Abuf, Wfrag2, b2_rel, ybuf);
    k_mixup_toA<<<elGrid, 256, 0, stream>>>(ybuf, perm2, lam, Abuf);
    // layer 3 (mixup3 is a pooling no-op -> fused pool)
    k_aggregate<<<aggGrid, 256, 0, stream>>>(Abuf, nodeseg, col2);
    k_gemm_pool<<<gemmGrid, 64, 0, stream>>>(Abuf, Wfrag2, b2_rel, pooled);

    // classifier + log_softmax
    k_final<<<NGRAPH, 64, 0, stream>>>(pooled, W_lin, b_lin, out);
}

// Round 14
// 302.738 us; speedup vs baseline: 1.3680x; 1.1077x over previous
//
#include <hip/hip_runtime.h>

#define N_NODES 51200
#define N_EDGES 819200
#define HDIM 128
#define AK 256          // GEMM K = 2*HDIM (agg | x)
#define NGRAPH 128
#define SEG 400
#define NOUT 10
#define SLOT 64         // fixed col2 slot per node (deg ~ Poisson(16); P(>64) ~ 1e-13)

typedef unsigned short ushort_t;
typedef unsigned int uint_t;
typedef __attribute__((ext_vector_type(8))) short bf16x8;
typedef __attribute__((ext_vector_type(16))) float f32x16;

static __device__ __forceinline__ unsigned short f2bf(float f) {
    unsigned int u = __float_as_uint(f);
    unsigned int r = (u + 0x7fffu + ((u >> 16) & 1u)) >> 16;  // RNE
    return (unsigned short)r;
}
static __device__ __forceinline__ float bf2f(unsigned short h) {
    return __uint_as_float(((unsigned int)h) << 16);
}

// ---------------- edge scatter: the ENTIRE CSR build in one kernel ----------------
// fixed 64-entry slot per node (R12); per-node cursor atomics (~16-way avg contention)

__global__ void k_scatter(const int* __restrict__ src, const int* __restrict__ dst,
                          int* __restrict__ cnt, ushort_t* __restrict__ col2) {
    int e = blockIdx.x * 256 + threadIdx.x;
    int d = dst[e];
    int pos = atomicAdd(&cnt[d], 1);
    col2[(size_t)d * SLOT + pos] = (ushort_t)src[e];
}

// ---------------- prep: cast x0 -> Abuf right half, build Wfrags, zero pooled --------
// grid = 6400 (cast) + 128 (wfrag1) + 128 (wfrag2) + 64 (pooled zero) = 6720

__global__ void k_prep(const float* __restrict__ x, ushort_t* __restrict__ Abuf,
                       const float* __restrict__ W1rel, const float* __restrict__ W1root,
                       const float* __restrict__ W2rel, const float* __restrict__ W2root,
                       ushort_t* __restrict__ Wfrag1, ushort_t* __restrict__ Wfrag2,
                       float* __restrict__ pooled) {
    int b = blockIdx.x;
    if (b < 6400) {
        int idx = b * 256 + threadIdx.x;
        int row = idx >> 5;
        int c4 = (idx & 31) * 4;
        float4 v = *(const float4*)(x + (size_t)row * HDIM + c4);
        ushort4 h;
        h.x = f2bf(v.x); h.y = f2bf(v.y); h.z = f2bf(v.z); h.w = f2bf(v.w);
        *(ushort4*)(Abuf + (size_t)row * AK + HDIM + c4) = h;
    } else if (b < 6656) {
        int w2 = (b >= 6528);
        int tid = (b - (w2 ? 6528 : 6400)) * 256 + threadIdx.x;  // 0..32767
        const float* Wrel  = w2 ? W2rel : W1rel;
        const float* Wroot = w2 ? W2root : W1root;
        ushort_t* dstF     = w2 ? Wfrag2 : Wfrag1;
        int j = tid & 7;
        int l = (tid >> 3) & 63;
        int s = (tid >> 9) & 15;
        int t = tid >> 13;
        int k = 16 * s + (l >> 5) * 8 + j;
        int n = 32 * t + (l & 31);
        float v = (k < HDIM) ? Wrel[(size_t)k * HDIM + n]
                             : Wroot[(size_t)(k - HDIM) * HDIM + n];
        dstF[tid] = f2bf(v);
    } else {
        int i = (b - 6656) * 256 + threadIdx.x;  // 0..16383
        pooled[i] = 0.f;
    }
}

// ---------------- aggregation: quad-edge 16B gathers (R13) ----------------
// 4 edges x 16 lanes x uint4 (8 bf16 cols/lane); stages 16/4/masked fit Poisson(16)

__global__ __launch_bounds__(256) void k_aggregate(ushort_t* __restrict__ Abuf,
                                                   const int* __restrict__ cnt,
                                                   const ushort_t* __restrict__ col) {
    int wave = threadIdx.x >> 6;
    int lane = threadIdx.x & 63;
    int il = lane & 15;          // col group: cols 8*il..8*il+7 (16 B)
    int qe = lane >> 4;          // edge within quad: 0..3
    int node = blockIdx.x * 4 + wave;
    int beg = node * SLOT;
    int end = beg + cnt[node];

    const ushort_t* xsrc = Abuf + HDIM + (size_t)il * 8;

    float a[4][8];
#pragma unroll
    for (int j = 0; j < 4; ++j)
#pragma unroll
        for (int k = 0; k < 8; ++k) a[j][k] = 0.f;

    int e = beg;
    // stage A: 16 edges per iter (4 quad-slots in flight, 4 KB/wave)
    for (; e + 16 <= end; e += 16) {
        int c[4];
#pragma unroll
        for (int j = 0; j < 4; ++j) c[j] = (int)col[e + 4 * j + qe];
#pragma unroll
        for (int j = 0; j < 4; ++j) {
            uint4 v = *(const uint4*)(xsrc + (size_t)c[j] * AK);
            a[j][0] += __uint_as_float(v.x << 16);
            a[j][1] += __uint_as_float(v.x & 0xffff0000u);
            a[j][2] += __uint_as_float(v.y << 16);
            a[j][3] += __uint_as_float(v.y & 0xffff0000u);
            a[j][4] += __uint_as_float(v.z << 16);
            a[j][5] += __uint_as_float(v.z & 0xffff0000u);
            a[j][6] += __uint_as_float(v.w << 16);
            a[j][7] += __uint_as_float(v.w & 0xffff0000u);
        }
    }
    // stage B: 4 edges per iter
    for (; e + 4 <= end; e += 4) {
        int c = (int)col[e + qe];
        uint4 v = *(const uint4*)(xsrc + (size_t)c * AK);
        a[0][0] += __uint_as_float(v.x << 16);
        a[0][1] += __uint_as_float(v.x & 0xffff0000u);
        a[0][2] += __uint_as_float(v.y << 16);
        a[0][3] += __uint_as_float(v.y & 0xffff0000u);
        a[0][4] += __uint_as_float(v.z << 16);
        a[0][5] += __uint_as_float(v.z & 0xffff0000u);
        a[0][6] += __uint_as_float(v.w << 16);
        a[0][7] += __uint_as_float(v.w & 0xffff0000u);
    }
    // stage C: masked tail (<4 edges)
    if (e < end) {
        int idx = e + qe;
        bool ok = idx < end;
        int c = (int)col[ok ? idx : e];
        uint4 v = *(const uint4*)(xsrc + (size_t)c * AK);
        a[1][0] += ok ? __uint_as_float(v.x << 16) : 0.f;
        a[1][1] += ok ? __uint_as_float(v.x & 0xffff0000u) : 0.f;
        a[1][2] += ok ? __uint_as_float(v.y << 16) : 0.f;
        a[1][3] += ok ? __uint_as_float(v.y & 0xffff0000u) : 0.f;
        a[1][4] += ok ? __uint_as_float(v.z << 16) : 0.f;
        a[1][5] += ok ? __uint_as_float(v.z & 0xffff0000u) : 0.f;
        a[1][6] += ok ? __uint_as_float(v.w << 16) : 0.f;
        a[1][7] += ok ? __uint_as_float(v.w & 0xffff0000u) : 0.f;
    }

    float s[8];
#pragma unroll
    for (int k = 0; k < 8; ++k) {
        s[k] = (a[0][k] + a[1][k]) + (a[2][k] + a[3][k]);
        s[k] += __shfl_xor(s[k], 16);
        s[k] += __shfl_xor(s[k], 32);
    }

    if (qe == 0) {
        uint4 o;
        o.x = (uint_t)f2bf(s[0]) | ((uint_t)f2bf(s[1]) << 16);
        o.y = (uint_t)f2bf(s[2]) | ((uint_t)f2bf(s[3]) << 16);
        o.z = (uint_t)f2bf(s[4]) | ((uint_t)f2bf(s[5]) << 16);
        o.w = (uint_t)f2bf(s[6]) | ((uint_t)f2bf(s[7]) << 16);
        *(uint4*)(Abuf + (size_t)node * AK + il * 8) = o;
    }
}

// ---------------- MFMA GEMM (layers 1-2): split-N, wave = 32 rows x 64 cols ---------

__global__ __launch_bounds__(64) void k_gemm_mfma(const ushort_t* __restrict__ Abuf,
                                                  const ushort_t* __restrict__ Wfrag,
                                                  const float* __restrict__ bias,
                                                  ushort_t* __restrict__ y) {
    __shared__ ushort_t sm[32][72];
    int lane = threadIdx.x;
    int nh = blockIdx.x & 1;
    int row0 = (blockIdx.x >> 1) * 32;
    int m = lane & 31;
    int half = lane >> 5;

    f32x16 acc[2];
#pragma unroll
    for (int t = 0; t < 2; ++t) acc[t] = (f32x16)(0.f);

    float bb[2];
#pragma unroll
    for (int t = 0; t < 2; ++t) bb[t] = bias[nh * 64 + t * 32 + m];

    const ushort_t* arow = Abuf + (size_t)(row0 + m) * AK + half * 8;
    const ushort_t* wf = Wfrag + (size_t)lane * 8 + (size_t)nh * 2 * 16 * 512;

#pragma unroll
    for (int s = 0; s < 16; ++s) {
        bf16x8 afrag = *(const bf16x8*)(arow + s * 16);
#pragma unroll
        for (int t = 0; t < 2; ++t) {
            bf16x8 bfrag = *(const bf16x8*)(wf + (size_t)(t * 16 + s) * 512);
            acc[t] = __builtin_amdgcn_mfma_f32_32x32x16_bf16(afrag, bfrag, acc[t], 0, 0, 0);
        }
    }

#pragma unroll
    for (int t = 0; t < 2; ++t) {
#pragma unroll
        for (int r = 0; r < 16; ++r) {
            int rowL = (r & 3) + 8 * (r >> 2) + 4 * half;
            sm[rowL][t * 32 + m] = f2bf(fmaxf(acc[t][r] + bb[t], 0.f));
        }
    }
    __syncthreads();
    int seg = lane & 7;
    int rbase = lane >> 3;
#pragma unroll
    for (int it = 0; it < 4; ++it) {
        int rowL = rbase + it * 8;
        int4 chunk = *(const int4*)&sm[rowL][seg * 8];
        *(int4*)(y + (size_t)(row0 + rowL) * HDIM + nh * 64 + seg * 8) = chunk;
    }
}

// ---------------- MFMA GEMM layer-3: split-N, relu -> per-graph pooled atomicAdd -----

__global__ __launch_bounds__(64) void k_gemm_pool(const ushort_t* __restrict__ Abuf,
                                                  const ushort_t* __restrict__ Wfrag,
                                                  const float* __restrict__ bias,
                                                  float* __restrict__ pooled) {
    int lane = threadIdx.x;
    int nh = blockIdx.x & 1;
    int row0 = (blockIdx.x >> 1) * 32;
    int m = lane & 31;
    int half = lane >> 5;

    f32x16 acc[2];
#pragma unroll
    for (int t = 0; t < 2; ++t) acc[t] = (f32x16)(0.f);

    float bb[2];
#pragma unroll
    for (int t = 0; t < 2; ++t) bb[t] = bias[nh * 64 + t * 32 + m];

    const ushort_t* arow = Abuf + (size_t)(row0 + m) * AK + half * 8;
    const ushort_t* wf = Wfrag + (size_t)lane * 8 + (size_t)nh * 2 * 16 * 512;

#pragma unroll
    for (int s = 0; s < 16; ++s) {
        bf16x8 afrag = *(const bf16x8*)(arow + s * 16);
#pragma unroll
        for (int t = 0; t < 2; ++t) {
            bf16x8 bfrag = *(const bf16x8*)(wf + (size_t)(t * 16 + s) * 512);
            acc[t] = __builtin_amdgcn_mfma_f32_32x32x16_bf16(afrag, bfrag, acc[t], 0, 0, 0);
        }
    }

    int g0 = row0 / SEG;
    int bnd = (g0 + 1) * SEG;
    int straddle = (row0 + 31 >= bnd);

#pragma unroll
    for (int t = 0; t < 2; ++t) {
        float s0 = 0.f, s1 = 0.f;
#pragma unroll
        for (int r = 0; r < 16; ++r) {
            int row = row0 + (r & 3) + 8 * (r >> 2) + 4 * half;
            float v = fmaxf(acc[t][r] + bb[t], 0.f);
            if (row < bnd) s0 += v; else s1 += v;
        }
        s0 += __shfl_xor(s0, 32);
        s1 += __shfl_xor(s1, 32);
        if (half == 0) {
            int coln = nh * 64 + t * 32 + m;
            atomicAdd(&pooled[g0 * HDIM + coln], s0);
            if (straddle) atomicAdd(&pooled[(g0 + 1) * HDIM + coln], s1);
        }
    }
}

// ---------------- mixup: bf16 y -> Abuf right half ----------------

__global__ void k_mixup_toA(const ushort_t* __restrict__ y, const int* __restrict__ perm,
                            const float* __restrict__ lam, ushort_t* __restrict__ Abuf) {
    int idx = blockIdx.x * 256 + threadIdx.x;
    int row = idx >> 5;
    int c4 = (idx & 31) * 4;
    float l = lam[0];
    float om = 1.f - l;
    int p = perm[row];
    ushort4 a = *(const ushort4*)(y + (size_t)row * HDIM + c4);
    ushort4 b = *(const ushort4*)(y + (size_t)p * HDIM + c4);
    ushort4 o;
    o.x = f2bf(l * bf2f(a.x) + om * bf2f(b.x));
    o.y = f2bf(l * bf2f(a.y) + om * bf2f(b.y));
    o.z = f2bf(l * bf2f(a.z) + om * bf2f(b.z));
    o.w = f2bf(l * bf2f(a.w) + om * bf2f(b.w));
    *(ushort4*)(Abuf + (size_t)row * AK + HDIM + c4) = o;
}

// ---------------- final: linear + log_softmax from pooled ----------------

__global__ __launch_bounds__(64) void k_final(const float* __restrict__ pooled,
                                              const float* __restrict__ Wlin,
                                              const float* __restrict__ blin,
                                              float* __restrict__ out) {
    int g = blockIdx.x;
    int lane = threadIdx.x;
    float2 v = *(const float2*)(pooled + (size_t)g * HDIM + lane * 2);
    float p[NOUT];
#pragma unroll
    for (int o = 0; o < NOUT; ++o)
        p[o] = v.x * Wlin[(size_t)(2 * lane) * NOUT + o] +
               v.y * Wlin[(size_t)(2 * lane + 1) * NOUT + o];
#pragma unroll
    for (int mask = 1; mask < 64; mask <<= 1)
#pragma unroll
        for (int o = 0; o < NOUT; ++o) p[o] += __shfl_xor(p[o], mask);
    if (lane == 0) {
        float lg[NOUT];
        float mx = -1e30f;
#pragma unroll
        for (int o = 0; o < NOUT; ++o) { lg[o] = p[o] + blin[o]; mx = fmaxf(mx, lg[o]); }
        float se = 0.f;
#pragma unroll
        for (int o = 0; o < NOUT; ++o) se += expf(lg[o] - mx);
        float lse = mx + logf(se);
#pragma unroll
        for (int o = 0; o < NOUT; ++o) out[g * NOUT + o] = lg[o] - lse;
    }
}

// ---------------- host ----------------

extern "C" void kernel_launch(void* const* d_in, const int* in_sizes, int n_in,
                              void* d_out, int out_size, void* d_ws, size_t ws_size,
                              hipStream_t stream) {
    const float* x0     = (const float*)d_in[0];
    const int*   edge   = (const int*)d_in[1];
    const int*   src    = edge;
    const int*   dst    = edge + N_EDGES;
    const float* lam    = (const float*)d_in[2];
    const int*   perm1  = (const int*)d_in[5];
    const int*   perm2  = (const int*)d_in[6];
    const float* W1_rel = (const float*)d_in[8];
    const float* b1_rel = (const float*)d_in[9];
    const float* W1_root= (const float*)d_in[10];
    const float* W2_rel = (const float*)d_in[11];
    const float* b2_rel = (const float*)d_in[12];
    const float* W2_root= (const float*)d_in[13];
    const float* W_lin  = (const float*)d_in[14];
    const float* b_lin  = (const float*)d_in[15];
    float* out = (float*)d_out;

    char* w = (char*)d_ws;
    size_t off = 0;
    auto alloc = [&](size_t bytes) -> void* {
        void* p = w + off;
        off = (off + bytes + 255) & ~(size_t)255;
        return p;
    };
    int* cnt       = (int*)alloc((size_t)N_NODES * 4);
    ushort_t* col2 = (ushort_t*)alloc((size_t)N_NODES * SLOT * 2);
    ushort_t* Abuf   = (ushort_t*)alloc((size_t)N_NODES * AK * 2);
    ushort_t* ybuf   = (ushort_t*)alloc((size_t)N_NODES * HDIM * 2);
    ushort_t* Wfrag1 = (ushort_t*)alloc(32768 * 2);
    ushort_t* Wfrag2 = (ushort_t*)alloc(32768 * 2);
    float* pooled    = (float*)alloc((size_t)NGRAPH * HDIM * 4);

    hipMemsetAsync(cnt, 0, (size_t)N_NODES * 4, stream);

    // CSR build: ONE scatter kernel (fixed slots, R12+R14)
    k_scatter<<<N_EDGES / 256, 256, 0, stream>>>(src, dst, cnt, col2);

    // prep: cast + wfrags + pooled zero
    k_prep<<<6720, 256, 0, stream>>>(x0, Abuf, W1_rel, W1_root, W2_rel, W2_root,
                                     Wfrag1, Wfrag2, pooled);

    const int aggGrid  = N_NODES / 4;
    const int gemmGrid = (N_NODES / 32) * 2;
    const int elGrid   = (N_NODES * HDIM / 4) / 256;

    // layer 1
    k_aggregate<<<aggGrid, 256, 0, stream>>>(Abuf, cnt, col2);
    k_gemm_mfma<<<gemmGrid, 64, 0, stream>>>(Abuf, Wfrag1, b1_rel, ybuf);
    k_mixup_toA<<<elGrid, 256, 0, stream>>>(ybuf, perm1, lam, Abuf);
    // layer 2
    k_aggregate<<<aggGrid, 256, 0, stream>>>(Abuf, cnt, col2);
    k_gemm_mfma<<<gemmGrid, 64, 0, stream>>>(Abuf, Wfrag2, b2_rel, ybuf);
    k_mixup_toA<<<elGrid, 256, 0, stream>>>(ybuf, perm2, lam, Abuf);
    // layer 3 (mixup3 is a pooling no-op -> fused pool)
    k_aggregate<<<aggGrid, 256, 0, stream>>>(Abuf, cnt, col2);
    k_gemm_pool<<<gemmGrid, 64, 0, stream>>>(Abuf, Wfrag2, b2_rel, pooled);

    // classifier + log_softmax
    k_final<<<NGRAPH, 64, 0, stream>>>(pooled, W_lin, b_lin, out);
}